// Round 14
// baseline (562.415 us; speedup 1.0000x reference)
//
#include <hip/hip_runtime.h>
#include <hip/hip_bf16.h>

constexpr int V   = 100000;
constexpr int E   = 1600000;
constexpr int NET = 10;
constexpr int KXW = 138;              // W_xi row length (2*64+10)
constexpr int NB  = (V + 255) / 256;  // 391 blocks over nodes
constexpr int GN  = 8;                // partial-CSR groups (≈ XCDs)
constexpr int GV  = GN * V;           // 800000
constexpr int NBG = (GV + 255) / 256; // 3125
constexpr float MUS   = 0.1125f;      // MU / S
constexpr float SP    = 0.025f;       // int8 P scale
constexpr float LOG2E = 1.44269504f;
constexpr float S2L   = 2.0f * SP * LOG2E;   // int8 P step in exp2 domain
constexpr float AS    = MUS / 127.0f;        // int8 A decode scale

typedef __attribute__((ext_vector_type(8))) short short8;
typedef __attribute__((ext_vector_type(4))) float float4v;

__device__ __forceinline__ float fast_tanh(float x) {
    return 1.0f - 2.0f * __builtin_amdgcn_rcpf(__expf(2.0f * x) + 1.0f);
}
__device__ __forceinline__ float bflo(unsigned u) { return __uint_as_float(u << 16); }
__device__ __forceinline__ float bfhi(unsigned u) { return __uint_as_float(u & 0xffff0000u); }
__device__ __forceinline__ short f2bf(float x) {
    union { __hip_bfloat16 b; short s; } u; u.b = __float2bfloat16(x); return u.s;
}

// ---------------------------------------------------------------------------
// 8-way histogram: countg[g][v], g = blockIdx&7 (same grid as scatterg).
// ---------------------------------------------------------------------------
__global__ __launch_bounds__(256) void histg_kernel(
    const int* __restrict__ xneis, int* __restrict__ countg)
{
    int e = blockIdx.x * 256 + threadIdx.x;
    if (e >= E) return;
    int g = blockIdx.x & (GN - 1);
    int nr = xneis[e];
    if (nr < V) atomicAdd(&countg[g * V + nr], 1);
}

__global__ __launch_bounds__(256) void cnt_tot_kernel(
    const int* __restrict__ countg, int* __restrict__ cnt_tot)
{
    int v = blockIdx.x * 256 + threadIdx.x;
    if (v >= V) return;
    int s = 0;
    #pragma unroll
    for (int g = 0; g < GN; ++g) s += countg[g * V + v];
    cnt_tot[v] = s;
}

// Generic block-exclusive scan: out[i] = exclusive scan within block; bsum[b]=total.
__global__ __launch_bounds__(256) void scan_block_kernel(
    const int* __restrict__ in, int* __restrict__ out, int* __restrict__ bsum, int n)
{
    __shared__ int s[256];
    int tid = threadIdx.x;
    int i = blockIdx.x * 256 + tid;
    int v = (i < n) ? in[i] : 0;
    s[tid] = v; __syncthreads();
    #pragma unroll
    for (int off = 1; off < 256; off <<= 1) {
        int t = (tid >= off) ? s[tid - off] : 0;
        __syncthreads();
        s[tid] += t;
        __syncthreads();
    }
    if (i < n) out[i] = s[tid] - v;
    if (tid == 255) bsum[blockIdx.x] = s[255];
}

__global__ __launch_bounds__(256) void add_gen_kernel(
    int* __restrict__ arr, const int* __restrict__ tops, int n)
{
    int i = blockIdx.x * 256 + threadIdx.x;
    if (i < n) arr[i] += tops[i >> 8];
}

// rowptr path (V entries + total), NB <= 512
__global__ __launch_bounds__(512) void scan_tops_kernel(
    const int* __restrict__ blocksum, int* __restrict__ tops, int* __restrict__ rowptr)
{
    __shared__ int s[512];
    int tid = threadIdx.x;
    int v = (tid < NB) ? blocksum[tid] : 0;
    s[tid] = v; __syncthreads();
    #pragma unroll
    for (int off = 1; off < 512; off <<= 1) {
        int t = (tid >= off) ? s[tid - off] : 0;
        __syncthreads();
        s[tid] += t;
        __syncthreads();
    }
    if (tid < NB) tops[tid] = s[tid] - v;        // exclusive
    if (tid == 511) rowptr[V] = s[511];          // total kept edges
}

__global__ __launch_bounds__(256) void add_offsets_kernel(
    const int* __restrict__ scanned, const int* __restrict__ tops, int* __restrict__ rowptr)
{
    int i = blockIdx.x * 256 + threadIdx.x;
    if (i < V) rowptr[i] = scanned[i] + tops[blockIdx.x];
}

// Scatter into group-g partial CSR (g = blockIdx&7, same grid as histg).
// meta word: src (17 b) | et (4 b) | dg-1 (6 b)
__global__ __launch_bounds__(256) void scatterg_kernel(
    const int* __restrict__ xnode, const int* __restrict__ xneis,
    const int* __restrict__ etype, const float* __restrict__ dg,
    const int* __restrict__ rpg, int* __restrict__ cursorg,
    unsigned* __restrict__ pmeta)
{
    int e = blockIdx.x * 256 + threadIdx.x;
    if (e >= E) return;
    int g = blockIdx.x & (GN - 1);
    int nr = xneis[e];
    if (nr < V) {
        int idx = g * V + nr;
        int p = rpg[idx] + atomicAdd(&cursorg[idx], 1);
        unsigned src = (unsigned)(xnode[e] - 1);
        unsigned et  = (unsigned)(etype[e] - 1);
        unsigned dgi = (unsigned)dg[e] - 1;        // 0..63, exact
        pmeta[p] = src | (et << 17) | (dgi << 21);
    }
}

// Merge 8 per-group segments of each node into the final node-major CSR.
__global__ __launch_bounds__(256) void merge_kernel(
    const int* __restrict__ countg, const int* __restrict__ rpg,
    const unsigned* __restrict__ pmeta, const int* __restrict__ rowptr,
    unsigned* __restrict__ meta)
{
    int v = blockIdx.x * 256 + threadIdx.x;
    if (v >= V) return;
    int off = rowptr[v];
    #pragma unroll
    for (int g = 0; g < GN; ++g) {
        int idx = g * V + v;
        int n = countg[idx];
        int base = rpg[idx];
        for (int i = 0; i < n; ++i) meta[off++] = pmeta[base + i];
    }
}

// ---------------------------------------------------------------------------
// Per-node bias sum + H_init row sums:
//   Bsum[v] = cnt_tot[v] * tanh(W_rou·feat[v-1]+b);  hs0[v] = sum(Hinit[v][:])
// ---------------------------------------------------------------------------
__global__ __launch_bounds__(256) void bsum_kernel(
    const float* __restrict__ feat, const int* __restrict__ count,
    const float* __restrict__ Wrou, const float* __restrict__ brou,
    const float* __restrict__ Hinit, float* __restrict__ Bsum,
    float* __restrict__ hs0)
{
    __shared__ float Wl[512];
    __shared__ float bl[8];
    int tid = threadIdx.x;
    for (int i = tid; i < 512; i += 256) Wl[i] = Wrou[i];
    if (tid < 8) bl[tid] = brou[tid];
    __syncthreads();

    int v = blockIdx.x * 256 + tid;
    if (v >= V) return;
    int c = count[v];
    float out[8] = {0, 0, 0, 0, 0, 0, 0, 0};
    if (c > 0) {                                  // c>0 implies v >= 1
        const float4* f4 = (const float4*)(feat + (size_t)(v - 1) * 64);
        float acc[8];
        #pragma unroll
        for (int s = 0; s < 8; ++s) acc[s] = bl[s];
        #pragma unroll 4
        for (int k = 0; k < 16; ++k) {
            float4 x = f4[k];
            #pragma unroll
            for (int s = 0; s < 8; ++s) {
                const float* w = &Wl[s * 64 + k * 4];
                acc[s] += x.x * w[0] + x.y * w[1] + x.z * w[2] + x.w * w[3];
            }
        }
        float fc = (float)c;
        #pragma unroll
        for (int s = 0; s < 8; ++s) out[s] = fc * fast_tanh(acc[s]);
    }
    float4* O = (float4*)(Bsum + (size_t)v * 8);
    O[0] = make_float4(out[0], out[1], out[2], out[3]);
    O[1] = make_float4(out[4], out[5], out[6], out[7]);

    // row sum of Hinit for the first step's bias-correction trick
    const float4* Hh = (const float4*)(Hinit + (size_t)v * 8);
    float4 ha = Hh[0], hb = Hh[1];
    hs0[v] = (ha.x + ha.y + ha.z + ha.w) + (hb.x + hb.y + hb.z + hb.w);
}

// ---------------------------------------------------------------------------
// PQ GEMM (MFMA): P[v] -> int8 biased (6.4 MB), Q[v] -> bf16 (12.8 MB)
// ---------------------------------------------------------------------------
__global__ __launch_bounds__(256) void pq_kernel(
    const float* __restrict__ feat, const float* __restrict__ Wxi,
    unsigned char* __restrict__ P8, ushort* __restrict__ Qb)
{
    const int lane = threadIdx.x & 63, wave = threadIdx.x >> 6;
    const int quad = lane >> 4, l16 = lane & 15;

    short8 bP[4][2], bQ[4][2];
    #pragma unroll
    for (int nt = 0; nt < 4; ++nt) {
        #pragma unroll
        for (int ks = 0; ks < 2; ++ks) {
            const float* wp = Wxi + (size_t)(nt * 16 + l16) * KXW + ks * 32 + quad * 8;
            short8 p, q;
            #pragma unroll
            for (int j = 0; j < 8; ++j) { p[j] = f2bf(wp[j]); q[j] = f2bf(wp[64 + j]); }
            bP[nt][ks] = p; bQ[nt][ks] = q;
        }
    }

    int t = blockIdx.x * 4 + wave;
    if (t >= V / 16) return;
    int v0 = t * 16;

    const float* fp = feat + (size_t)(v0 + l16) * 64 + quad * 8;
    short8 a0, a1;
    #pragma unroll
    for (int j = 0; j < 8; ++j) { a0[j] = f2bf(fp[j]); a1[j] = f2bf(fp[32 + j]); }

    float4v accP[4], accQ[4];
    #pragma unroll
    for (int nt = 0; nt < 4; ++nt) {
        float4v z = {0.f, 0.f, 0.f, 0.f};
        z = __builtin_amdgcn_mfma_f32_16x16x32_bf16(a0, bP[nt][0], z, 0, 0, 0);
        z = __builtin_amdgcn_mfma_f32_16x16x32_bf16(a1, bP[nt][1], z, 0, 0, 0);
        accP[nt] = z;
        float4v w = {0.f, 0.f, 0.f, 0.f};
        w = __builtin_amdgcn_mfma_f32_16x16x32_bf16(a0, bQ[nt][0], w, 0, 0, 0);
        w = __builtin_amdgcn_mfma_f32_16x16x32_bf16(a1, bQ[nt][1], w, 0, 0, 0);
        accQ[nt] = w;
    }

    #pragma unroll
    for (int r = 0; r < 4; ++r) {
        int row = v0 + quad * 4 + r;
        #pragma unroll
        for (int nt = 0; nt < 4; ++nt) {
            int col = nt * 16 + l16;
            int q8 = (int)rintf(accP[nt][r] * (1.0f / SP)) + 128;
            q8 = min(max(q8, 0), 255);
            P8[row * 64 + col] = (unsigned char)q8;
            Qb[row * 64 + col] = (ushort)f2bf(accQ[nt][r]);
        }
    }
}

// ---------------------------------------------------------------------------
// A materialization (once), int8 biased. Encode fused into tanh algebra:
//   tanh = 1-2r, q = tanh*(127/dg)+128.5 = fma(r, -2k, k+128.5), k=127/dg.
//   trunc((unsigned)) == round-nearest; range (1.5,255.5) -> no clamp needed.
// (r13 had mul,mul,rndne,add,min,max per element here — 4 ops saved/elem.)
// ---------------------------------------------------------------------------
__global__ __launch_bounds__(256) void amat_kernel(
    const unsigned* __restrict__ meta, const int* __restrict__ rowptr,
    const unsigned char* __restrict__ P8, const ushort* __restrict__ Qb,
    const float* __restrict__ Wxi, const float* __restrict__ bxi,
    unsigned char* __restrict__ A8)
{
    __shared__ float Wet2[NET * 64];     // 2*log2e*(Wxi[n][128+et]+bxi[n])
    __shared__ float scT[64];            // 127/dg
    int tid = threadIdx.x;
    for (int i = tid; i < NET * 64; i += 256) {
        int et = i >> 6, n = i & 63;
        Wet2[i] = 2.0f * LOG2E * (Wxi[n * KXW + 128 + et] + bxi[n]);
    }
    if (tid < 64) scT[tid] = 127.0f / (float)(tid + 1);
    __syncthreads();

    int v = blockIdx.x * 4 + (tid >> 6);
    if (v >= V) return;
    int lane = tid & 63;
    int el = lane >> 3, s = lane & 7;

    int p0 = rowptr[v], p1 = rowptr[v + 1];

    float q0, q1, q2, q3, q4, q5, q6, q7;
    {
        uint4 qu = *(const uint4*)(Qb + v * 64 + s * 8);
        const float B = 128.0f * SP, C = 2.0f * LOG2E;
        q0 = C * (bflo(qu.x) - B); q1 = C * (bfhi(qu.x) - B);
        q2 = C * (bflo(qu.y) - B); q3 = C * (bfhi(qu.y) - B);
        q4 = C * (bflo(qu.z) - B); q5 = C * (bfhi(qu.z) - B);
        q6 = C * (bflo(qu.w) - B); q7 = C * (bfhi(qu.w) - B);
    }

    for (int p = p0 + el; p < p1; p += 8) {
        unsigned m = meta[p];
        int src = (int)(m & 0x1FFFF);
        int et  = (int)((m >> 17) & 0xF);
        float k   = scT[m >> 21];
        float m2k = -2.0f * k;
        float ck  = k + 128.5f;

        uint2 pu = *(const uint2*)(P8 + src * 64 + s * 8);
        const float4* w4 = (const float4*)(&Wet2[et * 64 + s * 8]);
        float4 wa = w4[0], wb = w4[1];

        float r0 = __builtin_amdgcn_rcpf(__builtin_amdgcn_exp2f(fmaf((float)( pu.x        & 0xff), S2L, q0 + wa.x)) + 1.0f);
        float r1 = __builtin_amdgcn_rcpf(__builtin_amdgcn_exp2f(fmaf((float)((pu.x >>  8) & 0xff), S2L, q1 + wa.y)) + 1.0f);
        float r2 = __builtin_amdgcn_rcpf(__builtin_amdgcn_exp2f(fmaf((float)((pu.x >> 16) & 0xff), S2L, q2 + wa.z)) + 1.0f);
        float r3 = __builtin_amdgcn_rcpf(__builtin_amdgcn_exp2f(fmaf((float)( pu.x >> 24        ), S2L, q3 + wa.w)) + 1.0f);
        float r4 = __builtin_amdgcn_rcpf(__builtin_amdgcn_exp2f(fmaf((float)( pu.y        & 0xff), S2L, q4 + wb.x)) + 1.0f);
        float r5 = __builtin_amdgcn_rcpf(__builtin_amdgcn_exp2f(fmaf((float)((pu.y >>  8) & 0xff), S2L, q5 + wb.y)) + 1.0f);
        float r6 = __builtin_amdgcn_rcpf(__builtin_amdgcn_exp2f(fmaf((float)((pu.y >> 16) & 0xff), S2L, q6 + wb.z)) + 1.0f);
        float r7 = __builtin_amdgcn_rcpf(__builtin_amdgcn_exp2f(fmaf((float)( pu.y >> 24        ), S2L, q7 + wb.w)) + 1.0f);

        unsigned b0 = (unsigned)fmaf(r0, m2k, ck);
        unsigned b1 = (unsigned)fmaf(r1, m2k, ck);
        unsigned b2 = (unsigned)fmaf(r2, m2k, ck);
        unsigned b3 = (unsigned)fmaf(r3, m2k, ck);
        unsigned b4 = (unsigned)fmaf(r4, m2k, ck);
        unsigned b5 = (unsigned)fmaf(r5, m2k, ck);
        unsigned b6 = (unsigned)fmaf(r6, m2k, ck);
        unsigned b7 = (unsigned)fmaf(r7, m2k, ck);

        uint2 o;
        o.x = b0 | (b1 << 8) | (b2 << 16) | (b3 << 24);
        o.y = b4 | (b5 << 8) | (b6 << 16) | (b7 << 24);
        *(uint2*)(A8 + p * 64 + s * 8) = o;
    }
}

// ---------------------------------------------------------------------------
// Light step with hoisted bias: sum (q-128)·h = sum q·h - 128·rowsum(h).
// hsIn[src] supplies rowsum(H[src]) (computed in previous step's epilogue /
// bsum for H_init) — kills 8 subs + 7 adds per edge-lane vs r13.
// ---------------------------------------------------------------------------
__global__ __launch_bounds__(256) void step_kernel(
    const float* __restrict__ Hin, const float* __restrict__ hsIn,
    float* __restrict__ Hout, float* __restrict__ hsOut,
    const unsigned* __restrict__ meta, const int* __restrict__ rowptr,
    const unsigned char* __restrict__ A8, const float* __restrict__ Bsum,
    const float* __restrict__ W1, const float* __restrict__ b1,
    float* __restrict__ logitsOut)
{
    int v = blockIdx.x * 4 + (threadIdx.x >> 6);
    if (v >= V) return;
    int lane = threadIdx.x & 63;
    int el = lane >> 3, s = lane & 7;

    int p0 = rowptr[v], p1 = rowptr[v + 1];

    float acc = 0.0f, csum = 0.0f;
    for (int p = p0 + el; p < p1; p += 8) {
        int src = (int)(meta[p] & 0x1FFFF);
        uint2 au = *(const uint2*)(A8 + p * 64 + s * 8);
        float4 h0 = *(const float4*)(Hin + src * 8);
        float4 h1 = *(const float4*)(Hin + src * 8 + 4);
        float hs = hsIn[src];

        float d;
        d  = (float)( au.x        & 0xff) * h0.x;
        d += (float)((au.x >>  8) & 0xff) * h0.y;
        d += (float)((au.x >> 16) & 0xff) * h0.z;
        d += (float)( au.x >> 24        ) * h0.w;
        d += (float)( au.y        & 0xff) * h1.x;
        d += (float)((au.y >>  8) & 0xff) * h1.y;
        d += (float)((au.y >> 16) & 0xff) * h1.z;
        d += (float)( au.y >> 24        ) * h1.w;
        acc  += d;
        csum += hs;
    }
    acc  += __shfl_xor(acc, 8);  acc  += __shfl_xor(acc, 16);  acc  += __shfl_xor(acc, 32);
    csum += __shfl_xor(csum, 8); csum += __shfl_xor(csum, 16); csum += __shfl_xor(csum, 32);

    float hfin = (acc - 128.0f * csum) * AS + Bsum[v * 8 + s];

    // row sum of the new H for the NEXT step's correction term
    float t2 = hfin;
    t2 += __shfl_xor(t2, 1); t2 += __shfl_xor(t2, 2); t2 += __shfl_xor(t2, 4);
    if (el == 0) {
        Hout[v * 8 + s] = hfin;
        if (lane == 0) hsOut[v] = t2;
    }

    if (logitsOut != nullptr) {
        float t = hfin * W1[s];
        t += __shfl_xor(t, 1); t += __shfl_xor(t, 2); t += __shfl_xor(t, 4);
        if (lane == 0) logitsOut[v] = t + b1[0];
    }
}

// ---------------------------------------------------------------------------
// Epilogue
// ---------------------------------------------------------------------------
__global__ __launch_bounds__(256) void reduce_max_kernel(
    const float* __restrict__ logits, float* __restrict__ partial)
{
    float m = -INFINITY;
    for (int v = blockIdx.x * 256 + threadIdx.x; v < V; v += 256 * 256)
        m = fmaxf(m, logits[v]);
    #pragma unroll
    for (int o = 32; o > 0; o >>= 1) m = fmaxf(m, __shfl_down(m, o));
    __shared__ float sm[4];
    if ((threadIdx.x & 63) == 0) sm[threadIdx.x >> 6] = m;
    __syncthreads();
    if (threadIdx.x == 0)
        partial[blockIdx.x] = fmaxf(fmaxf(sm[0], sm[1]), fmaxf(sm[2], sm[3]));
}

__global__ __launch_bounds__(256) void final_max_kernel(
    const float* __restrict__ partial, float* __restrict__ M)
{
    float m = partial[threadIdx.x];
    #pragma unroll
    for (int o = 32; o > 0; o >>= 1) m = fmaxf(m, __shfl_down(m, o));
    __shared__ float sm[4];
    if ((threadIdx.x & 63) == 0) sm[threadIdx.x >> 6] = m;
    __syncthreads();
    if (threadIdx.x == 0) *M = fmaxf(fmaxf(sm[0], sm[1]), fmaxf(sm[2], sm[3]));
}

// Stage 1: 64 blocks write per-block partials (9 floats each) — no atomics.
__global__ __launch_bounds__(256) void sum_kernel(
    const float* __restrict__ H, const float* __restrict__ logits,
    const float* __restrict__ Mp, float* __restrict__ partial)
{
    const float M = *Mp;
    float se = 0.0f;
    float sh[8] = {0, 0, 0, 0, 0, 0, 0, 0};
    for (int v = blockIdx.x * 256 + threadIdx.x; v < V; v += 64 * 256) {
        float w = __expf(logits[v] - M);
        se += w;
        const float4* H4 = (const float4*)(H + (size_t)v * 8);
        float4 h0 = H4[0], h1 = H4[1];
        sh[0] += w * h0.x; sh[1] += w * h0.y; sh[2] += w * h0.z; sh[3] += w * h0.w;
        sh[4] += w * h1.x; sh[5] += w * h1.y; sh[6] += w * h1.z; sh[7] += w * h1.w;
    }
    #pragma unroll
    for (int o = 32; o > 0; o >>= 1) {
        se += __shfl_xor(se, o);
        #pragma unroll
        for (int i = 0; i < 8; ++i) sh[i] += __shfl_xor(sh[i], o);
    }
    __shared__ float sm[4][9];
    int wv = threadIdx.x >> 6;
    if ((threadIdx.x & 63) == 0) {
        sm[wv][8] = se;
        #pragma unroll
        for (int i = 0; i < 8; ++i) sm[wv][i] = sh[i];
    }
    __syncthreads();
    if (threadIdx.x == 0) {
        #pragma unroll
        for (int i = 0; i < 9; ++i)
            partial[blockIdx.x * 12 + i] = sm[0][i] + sm[1][i] + sm[2][i] + sm[3][i];
    }
}

__global__ void final_kernel(const float* __restrict__ partial, float* __restrict__ out)
{
    int lane = threadIdx.x;               // 64 threads
    float vals[9];
    #pragma unroll
    for (int i = 0; i < 9; ++i) vals[i] = partial[lane * 12 + i];
    #pragma unroll
    for (int o = 1; o < 64; o <<= 1) {
        #pragma unroll
        for (int i = 0; i < 9; ++i) vals[i] += __shfl_xor(vals[i], o);
    }
    __shared__ float res[9];
    if (lane == 0) {
        #pragma unroll
        for (int i = 0; i < 9; ++i) res[i] = vals[i];
    }
    __syncthreads();
    if (lane < 8) out[lane] = tanhf(res[lane] / res[8]);
}

// ---------------------------------------------------------------------------
extern "C" void kernel_launch(void* const* d_in, const int* in_sizes, int n_in,
                              void* d_out, int out_size, void* d_ws, size_t ws_size,
                              hipStream_t stream)
{
    const float* feat  = (const float*)d_in[0];
    const int*   xnode = (const int*)d_in[1];
    const int*   xneis = (const int*)d_in[2];
    const int*   etype = (const int*)d_in[3];
    const float* dg    = (const float*)d_in[4];
    const float* Hinit = (const float*)d_in[5];
    const float* Wxi   = (const float*)d_in[6];
    const float* bxi   = (const float*)d_in[7];
    const float* Wrou  = (const float*)d_in[8];
    const float* brou  = (const float*)d_in[9];
    const float* W1    = (const float*)d_in[10];
    const float* b1    = (const float*)d_in[11];

    char* ws = (char*)d_ws;
    auto alloc = [&](size_t bytes) -> char* {
        char* p = ws; ws += (bytes + 255) & ~(size_t)255; return p;
    };
    // Budget: ~162 MB total (fits 256 MiB ws)
    unsigned char* A8 = (unsigned char*)alloc((size_t)E * 64); // 102.4 MB int8 A
    unsigned char* P8 = (unsigned char*)alloc((size_t)V * 64); // 6.4 MB int8 P
    ushort*   Qb      = (ushort*)alloc((size_t)V * 64 * 2);    // 12.8 MB bf16 Q
    unsigned* meta    = (unsigned*)alloc((size_t)E * 4);       // 6.4 MB final CSR
    unsigned* pmeta   = (unsigned*)alloc((size_t)E * 4);       // 6.4 MB partial CSR
    int*      countg  = (int*)alloc((size_t)2 * GV * 4);       // countg + cursorg
    int*      cursorg = countg + GV;
    int*      rpg     = (int*)alloc((size_t)GV * 4);           // 3.2 MB
    int*      cnt_tot = (int*)alloc((size_t)V * 4);
    int*      scannedT= (int*)alloc((size_t)V * 4);
    int*      rowptr  = (int*)alloc((size_t)(V + 1) * 4);
    int*      bsumT   = (int*)alloc(512 * 4);
    int*      topsT   = (int*)alloc(512 * 4);
    int*      bsumA   = (int*)alloc((size_t)NBG * 4);
    int*      sA      = (int*)alloc((size_t)NBG * 4);
    int*      bsumB   = (int*)alloc(64 * 4);
    int*      sB      = (int*)alloc(64 * 4);
    int*      bsumC   = (int*)alloc(16 * 4);
    float*    B0      = (float*)alloc((size_t)V * 8 * 4);
    float*    B1      = (float*)alloc((size_t)V * 8 * 4);
    float*    Bsum    = (float*)alloc((size_t)V * 8 * 4);
    float*    hs0     = (float*)alloc((size_t)V * 4);
    float*    hsA     = (float*)alloc((size_t)V * 4);
    float*    hsB     = (float*)alloc((size_t)V * 4);
    float*    logits  = (float*)alloc((size_t)V * 4);
    float*    pmax    = (float*)alloc(256 * 4);
    float*    Mp      = (float*)alloc(16);
    float*    spart   = (float*)alloc(64 * 12 * 4);

    hipMemsetAsync(countg, 0, (size_t)2 * GV * 4, stream);
    histg_kernel<<<(E + 255) / 256, 256, 0, stream>>>(xneis, countg);
    cnt_tot_kernel<<<NB, 256, 0, stream>>>(countg, cnt_tot);
    // rowptr = scan(cnt_tot), with total at rowptr[V]
    scan_block_kernel<<<NB, 256, 0, stream>>>(cnt_tot, scannedT, bsumT, V);
    scan_tops_kernel<<<1, 512, 0, stream>>>(bsumT, topsT, rowptr);
    add_offsets_kernel<<<NB, 256, 0, stream>>>(scannedT, topsT, rowptr);
    // rpg = scan(countg) over the concatenated [g][v] array (3-level)
    scan_block_kernel<<<NBG, 256, 0, stream>>>(countg, rpg, bsumA, GV);
    scan_block_kernel<<<(NBG + 255) / 256, 256, 0, stream>>>(bsumA, sA, bsumB, NBG);
    scan_block_kernel<<<1, 256, 0, stream>>>(bsumB, sB, bsumC, (NBG + 255) / 256);
    add_gen_kernel<<<(NBG + 255) / 256, 256, 0, stream>>>(sA, sB, NBG);
    add_gen_kernel<<<NBG, 256, 0, stream>>>(rpg, sA, GV);

    scatterg_kernel<<<(E + 255) / 256, 256, 0, stream>>>(xnode, xneis, etype, dg,
                                                         rpg, cursorg, pmeta);
    merge_kernel<<<NB, 256, 0, stream>>>(countg, rpg, pmeta, rowptr, meta);
    pq_kernel<<<(V / 16 + 3) / 4, 256, 0, stream>>>(feat, Wxi, P8, Qb);
    bsum_kernel<<<NB, 256, 0, stream>>>(feat, cnt_tot, Wrou, brou, Hinit, Bsum, hs0);
    amat_kernel<<<(V + 3) / 4, 256, 0, stream>>>(meta, rowptr, P8, Qb, Wxi, bxi, A8);

    const float* Hcur = Hinit;
    const float* hsCur = hs0;
    float* bufs[2]   = {B0, B1};
    float* hsbufs[2] = {hsA, hsB};
    for (int t = 0; t < 4; ++t) {
        float* Hn  = bufs[t & 1];
        float* hsn = hsbufs[t & 1];
        float* lg  = (t == 3) ? logits : nullptr;
        step_kernel<<<(V + 3) / 4, 256, 0, stream>>>(Hcur, hsCur, Hn, hsn,
                                                     meta, rowptr, A8, Bsum,
                                                     W1, b1, lg);
        Hcur = Hn; hsCur = hsn;
    }

    reduce_max_kernel<<<256, 256, 0, stream>>>(logits, pmax);
    final_max_kernel<<<1, 256, 0, stream>>>(pmax, Mp);
    sum_kernel<<<64, 256, 0, stream>>>(Hcur, logits, Mp, spart);
    final_kernel<<<1, 64, 0, stream>>>(spart, (float*)d_out);
}

// Round 15
// 536.088 us; speedup vs baseline: 1.0491x; 1.0491x over previous
//
#include <hip/hip_runtime.h>
#include <hip/hip_bf16.h>

constexpr int V   = 100000;
constexpr int E   = 1600000;
constexpr int NET = 10;
constexpr int KXW = 138;              // W_xi row length (2*64+10)
constexpr int NB  = (V + 255) / 256;  // 391 blocks over nodes
constexpr int GN  = 8;                // partial-CSR groups (≈ XCDs)
constexpr int GV  = GN * V;           // 800000
constexpr int NBG = (GV + 255) / 256; // 3125
constexpr float MUS   = 0.1125f;      // MU / S
constexpr float SP    = 0.025f;       // int8 P scale
constexpr float LOG2E = 1.44269504f;
constexpr float S2L   = 2.0f * SP * LOG2E;   // int8 P step in exp2 domain
constexpr float AS    = MUS / 127.0f;        // int8 A decode scale

typedef __attribute__((ext_vector_type(8))) short short8;
typedef __attribute__((ext_vector_type(4))) float float4v;

__device__ __forceinline__ float fast_tanh(float x) {
    return 1.0f - 2.0f * __builtin_amdgcn_rcpf(__expf(2.0f * x) + 1.0f);
}
__device__ __forceinline__ float bflo(unsigned u) { return __uint_as_float(u << 16); }
__device__ __forceinline__ float bfhi(unsigned u) { return __uint_as_float(u & 0xffff0000u); }
__device__ __forceinline__ short f2bf(float x) {
    union { __hip_bfloat16 b; short s; } u; u.b = __float2bfloat16(x); return u.s;
}

// ---------------------------------------------------------------------------
// 8-way histogram: countg[g][v], g = blockIdx&7 (same grid as scatterg).
// ---------------------------------------------------------------------------
__global__ __launch_bounds__(256) void histg_kernel(
    const int* __restrict__ xneis, int* __restrict__ countg)
{
    int e = blockIdx.x * 256 + threadIdx.x;
    if (e >= E) return;
    int g = blockIdx.x & (GN - 1);
    int nr = xneis[e];
    if (nr < V) atomicAdd(&countg[g * V + nr], 1);
}

// Fused: cnt_tot[v] = sum_g countg[g][v]; blockwise-exclusive scan of cnt_tot.
__global__ __launch_bounds__(256) void scanV_kernel(
    const int* __restrict__ countg, int* __restrict__ cnt_tot,
    int* __restrict__ scanned, int* __restrict__ bsum)
{
    __shared__ int s[256];
    int tid = threadIdx.x;
    int i = blockIdx.x * 256 + tid;
    int c = 0;
    if (i < V) {
        #pragma unroll
        for (int g = 0; g < GN; ++g) c += countg[g * V + i];
        cnt_tot[i] = c;
    }
    s[tid] = c; __syncthreads();
    #pragma unroll
    for (int off = 1; off < 256; off <<= 1) {
        int t = (tid >= off) ? s[tid - off] : 0;
        __syncthreads();
        s[tid] += t;
        __syncthreads();
    }
    if (i < V) scanned[i] = s[tid] - c;
    if (tid == 255) bsum[blockIdx.x] = s[255];
}

// Generic block-exclusive scan (used for the GV level-0 scan).
__global__ __launch_bounds__(256) void scan_block_kernel(
    const int* __restrict__ in, int* __restrict__ out, int* __restrict__ bsum, int n)
{
    __shared__ int s[256];
    int tid = threadIdx.x;
    int i = blockIdx.x * 256 + tid;
    int v = (i < n) ? in[i] : 0;
    s[tid] = v; __syncthreads();
    #pragma unroll
    for (int off = 1; off < 256; off <<= 1) {
        int t = (tid >= off) ? s[tid - off] : 0;
        __syncthreads();
        s[tid] += t;
        __syncthreads();
    }
    if (i < n) out[i] = s[tid] - v;
    if (tid == 255) bsum[blockIdx.x] = s[255];
}

// Single-block full exclusive scan with running carry (replaces 2 scan levels
// + 1 add pass of the old 3-level GV scan).
__global__ __launch_bounds__(256) void scan_mid_kernel(
    const int* __restrict__ in, int* __restrict__ out, int n)
{
    __shared__ int s[256];
    __shared__ int carry;
    int tid = threadIdx.x;
    if (tid == 0) carry = 0;
    __syncthreads();
    for (int base = 0; base < n; base += 256) {
        int i = base + tid;
        int x = (i < n) ? in[i] : 0;
        s[tid] = x; __syncthreads();
        #pragma unroll
        for (int off = 1; off < 256; off <<= 1) {
            int t = (tid >= off) ? s[tid - off] : 0;
            __syncthreads();
            s[tid] += t;
            __syncthreads();
        }
        int incl = s[tid];
        int c = carry;
        if (i < n) out[i] = c + incl - x;
        __syncthreads();
        if (tid == 255) carry = c + incl;
        __syncthreads();
    }
}

__global__ __launch_bounds__(256) void add_gen_kernel(
    int* __restrict__ arr, const int* __restrict__ tops, int n)
{
    int i = blockIdx.x * 256 + threadIdx.x;
    if (i < n) arr[i] += tops[i >> 8];
}

// rowptr path (V entries + total), NB <= 512
__global__ __launch_bounds__(512) void scan_tops_kernel(
    const int* __restrict__ blocksum, int* __restrict__ tops, int* __restrict__ rowptr)
{
    __shared__ int s[512];
    int tid = threadIdx.x;
    int v = (tid < NB) ? blocksum[tid] : 0;
    s[tid] = v; __syncthreads();
    #pragma unroll
    for (int off = 1; off < 512; off <<= 1) {
        int t = (tid >= off) ? s[tid - off] : 0;
        __syncthreads();
        s[tid] += t;
        __syncthreads();
    }
    if (tid < NB) tops[tid] = s[tid] - v;        // exclusive
    if (tid == 511) rowptr[V] = s[511];          // total kept edges
}

__global__ __launch_bounds__(256) void add_offsets_kernel(
    const int* __restrict__ scanned, const int* __restrict__ tops, int* __restrict__ rowptr)
{
    int i = blockIdx.x * 256 + threadIdx.x;
    if (i < V) rowptr[i] = scanned[i] + tops[blockIdx.x];
}

// Scatter into group-g partial CSR (g = blockIdx&7, same grid as histg).
// meta word: src (17 b) | et (4 b) | dg-1 (6 b)
__global__ __launch_bounds__(256) void scatterg_kernel(
    const int* __restrict__ xnode, const int* __restrict__ xneis,
    const int* __restrict__ etype, const float* __restrict__ dg,
    const int* __restrict__ rpg, int* __restrict__ cursorg,
    unsigned* __restrict__ pmeta)
{
    int e = blockIdx.x * 256 + threadIdx.x;
    if (e >= E) return;
    int g = blockIdx.x & (GN - 1);
    int nr = xneis[e];
    if (nr < V) {
        int idx = g * V + nr;
        int p = rpg[idx] + atomicAdd(&cursorg[idx], 1);
        unsigned src = (unsigned)(xnode[e] - 1);
        unsigned et  = (unsigned)(etype[e] - 1);
        unsigned dgi = (unsigned)dg[e] - 1;        // 0..63, exact
        pmeta[p] = src | (et << 17) | (dgi << 21);
    }
}

// ---------------------------------------------------------------------------
// Per-node bias sum + H_init row sums.
// ---------------------------------------------------------------------------
__global__ __launch_bounds__(256) void bsum_kernel(
    const float* __restrict__ feat, const int* __restrict__ count,
    const float* __restrict__ Wrou, const float* __restrict__ brou,
    const float* __restrict__ Hinit, float* __restrict__ Bsum,
    float* __restrict__ hs0)
{
    __shared__ float Wl[512];
    __shared__ float bl[8];
    int tid = threadIdx.x;
    for (int i = tid; i < 512; i += 256) Wl[i] = Wrou[i];
    if (tid < 8) bl[tid] = brou[tid];
    __syncthreads();

    int v = blockIdx.x * 256 + tid;
    if (v >= V) return;
    int c = count[v];
    float out[8] = {0, 0, 0, 0, 0, 0, 0, 0};
    if (c > 0) {                                  // c>0 implies v >= 1
        const float4* f4 = (const float4*)(feat + (size_t)(v - 1) * 64);
        float acc[8];
        #pragma unroll
        for (int s = 0; s < 8; ++s) acc[s] = bl[s];
        #pragma unroll 4
        for (int k = 0; k < 16; ++k) {
            float4 x = f4[k];
            #pragma unroll
            for (int s = 0; s < 8; ++s) {
                const float* w = &Wl[s * 64 + k * 4];
                acc[s] += x.x * w[0] + x.y * w[1] + x.z * w[2] + x.w * w[3];
            }
        }
        float fc = (float)c;
        #pragma unroll
        for (int s = 0; s < 8; ++s) out[s] = fc * fast_tanh(acc[s]);
    }
    float4* O = (float4*)(Bsum + (size_t)v * 8);
    O[0] = make_float4(out[0], out[1], out[2], out[3]);
    O[1] = make_float4(out[4], out[5], out[6], out[7]);

    const float4* Hh = (const float4*)(Hinit + (size_t)v * 8);
    float4 ha = Hh[0], hb = Hh[1];
    hs0[v] = (ha.x + ha.y + ha.z + ha.w) + (hb.x + hb.y + hb.z + hb.w);
}

// ---------------------------------------------------------------------------
// PQ GEMM (MFMA): P[v] -> int8 biased (6.4 MB), Q[v] -> bf16 (12.8 MB)
// ---------------------------------------------------------------------------
__global__ __launch_bounds__(256) void pq_kernel(
    const float* __restrict__ feat, const float* __restrict__ Wxi,
    unsigned char* __restrict__ P8, ushort* __restrict__ Qb)
{
    const int lane = threadIdx.x & 63, wave = threadIdx.x >> 6;
    const int quad = lane >> 4, l16 = lane & 15;

    short8 bP[4][2], bQ[4][2];
    #pragma unroll
    for (int nt = 0; nt < 4; ++nt) {
        #pragma unroll
        for (int ks = 0; ks < 2; ++ks) {
            const float* wp = Wxi + (size_t)(nt * 16 + l16) * KXW + ks * 32 + quad * 8;
            short8 p, q;
            #pragma unroll
            for (int j = 0; j < 8; ++j) { p[j] = f2bf(wp[j]); q[j] = f2bf(wp[64 + j]); }
            bP[nt][ks] = p; bQ[nt][ks] = q;
        }
    }

    int t = blockIdx.x * 4 + wave;
    if (t >= V / 16) return;
    int v0 = t * 16;

    const float* fp = feat + (size_t)(v0 + l16) * 64 + quad * 8;
    short8 a0, a1;
    #pragma unroll
    for (int j = 0; j < 8; ++j) { a0[j] = f2bf(fp[j]); a1[j] = f2bf(fp[32 + j]); }

    float4v accP[4], accQ[4];
    #pragma unroll
    for (int nt = 0; nt < 4; ++nt) {
        float4v z = {0.f, 0.f, 0.f, 0.f};
        z = __builtin_amdgcn_mfma_f32_16x16x32_bf16(a0, bP[nt][0], z, 0, 0, 0);
        z = __builtin_amdgcn_mfma_f32_16x16x32_bf16(a1, bP[nt][1], z, 0, 0, 0);
        accP[nt] = z;
        float4v w = {0.f, 0.f, 0.f, 0.f};
        w = __builtin_amdgcn_mfma_f32_16x16x32_bf16(a0, bQ[nt][0], w, 0, 0, 0);
        w = __builtin_amdgcn_mfma_f32_16x16x32_bf16(a1, bQ[nt][1], w, 0, 0, 0);
        accQ[nt] = w;
    }

    #pragma unroll
    for (int r = 0; r < 4; ++r) {
        int row = v0 + quad * 4 + r;
        #pragma unroll
        for (int nt = 0; nt < 4; ++nt) {
            int col = nt * 16 + l16;
            int q8 = (int)rintf(accP[nt][r] * (1.0f / SP)) + 128;
            q8 = min(max(q8, 0), 255);
            P8[row * 64 + col] = (unsigned char)q8;
            Qb[row * 64 + col] = (ushort)f2bf(accQ[nt][r]);
        }
    }
}

// ---------------------------------------------------------------------------
// A materialization + CSR finalization in ONE pass (merge_kernel eliminated):
// per node, walk the 8 group segments of pmeta (8-entry prefix table via
// shfl), compute int8 A rows, write A8 + esrc in final NODE-MAJOR order.
// ---------------------------------------------------------------------------
__global__ __launch_bounds__(256) void amat_kernel(
    const unsigned* __restrict__ pmeta, const int* __restrict__ countg,
    const int* __restrict__ rpg, const int* __restrict__ rowptr,
    const unsigned char* __restrict__ P8, const ushort* __restrict__ Qb,
    const float* __restrict__ Wxi, const float* __restrict__ bxi,
    unsigned char* __restrict__ A8, int* __restrict__ esrc)
{
    __shared__ float Wet2[NET * 64];     // 2*log2e*(Wxi[n][128+et]+bxi[n])
    __shared__ float scT[64];            // 127/dg
    int tid = threadIdx.x;
    for (int i = tid; i < NET * 64; i += 256) {
        int et = i >> 6, n = i & 63;
        Wet2[i] = 2.0f * LOG2E * (Wxi[n * KXW + 128 + et] + bxi[n]);
    }
    if (tid < 64) scT[tid] = 127.0f / (float)(tid + 1);
    __syncthreads();

    int v = blockIdx.x * 4 + (tid >> 6);
    if (v >= V) return;
    int lane = tid & 63;
    int el = lane >> 3, s = lane & 7;

    // 8-segment table (count, base) -> prefix
    int cg = 0, bg = 0;
    if (lane < 8) { cg = countg[lane * V + v]; bg = rpg[lane * V + v]; }
    int prefA[8], baseA[8];
    int pref = 0;
    #pragma unroll
    for (int g = 0; g < GN; ++g) {
        prefA[g] = pref;
        baseA[g] = __shfl(bg, g);
        pref += __shfl(cg, g);
    }
    const int deg = pref;
    const int off = rowptr[v];

    float q0, q1, q2, q3, q4, q5, q6, q7;
    {
        uint4 qu = *(const uint4*)(Qb + v * 64 + s * 8);
        const float B = 128.0f * SP, C = 2.0f * LOG2E;
        q0 = C * (bflo(qu.x) - B); q1 = C * (bfhi(qu.x) - B);
        q2 = C * (bflo(qu.y) - B); q3 = C * (bfhi(qu.y) - B);
        q4 = C * (bflo(qu.z) - B); q5 = C * (bfhi(qu.z) - B);
        q6 = C * (bflo(qu.w) - B); q7 = C * (bfhi(qu.w) - B);
    }

    for (int i = el; i < deg; i += 8) {
        int gg = 0;
        #pragma unroll
        for (int g = 1; g < GN; ++g) if (i >= prefA[g]) gg = g;
        int p = baseA[gg] + (i - prefA[gg]);
        unsigned m = pmeta[p];
        int src = (int)(m & 0x1FFFF);
        int et  = (int)((m >> 17) & 0xF);
        float k   = scT[m >> 21];
        float m2k = -2.0f * k;
        float ck  = k + 128.5f;

        uint2 pu = *(const uint2*)(P8 + src * 64 + s * 8);
        const float4* w4 = (const float4*)(&Wet2[et * 64 + s * 8]);
        float4 wa = w4[0], wb = w4[1];

        float r0 = __builtin_amdgcn_rcpf(__builtin_amdgcn_exp2f(fmaf((float)( pu.x        & 0xff), S2L, q0 + wa.x)) + 1.0f);
        float r1 = __builtin_amdgcn_rcpf(__builtin_amdgcn_exp2f(fmaf((float)((pu.x >>  8) & 0xff), S2L, q1 + wa.y)) + 1.0f);
        float r2 = __builtin_amdgcn_rcpf(__builtin_amdgcn_exp2f(fmaf((float)((pu.x >> 16) & 0xff), S2L, q2 + wa.z)) + 1.0f);
        float r3 = __builtin_amdgcn_rcpf(__builtin_amdgcn_exp2f(fmaf((float)( pu.x >> 24        ), S2L, q3 + wa.w)) + 1.0f);
        float r4 = __builtin_amdgcn_rcpf(__builtin_amdgcn_exp2f(fmaf((float)( pu.y        & 0xff), S2L, q4 + wb.x)) + 1.0f);
        float r5 = __builtin_amdgcn_rcpf(__builtin_amdgcn_exp2f(fmaf((float)((pu.y >>  8) & 0xff), S2L, q5 + wb.y)) + 1.0f);
        float r6 = __builtin_amdgcn_rcpf(__builtin_amdgcn_exp2f(fmaf((float)((pu.y >> 16) & 0xff), S2L, q6 + wb.z)) + 1.0f);
        float r7 = __builtin_amdgcn_rcpf(__builtin_amdgcn_exp2f(fmaf((float)( pu.y >> 24        ), S2L, q7 + wb.w)) + 1.0f);

        unsigned b0 = (unsigned)fmaf(r0, m2k, ck);
        unsigned b1 = (unsigned)fmaf(r1, m2k, ck);
        unsigned b2 = (unsigned)fmaf(r2, m2k, ck);
        unsigned b3 = (unsigned)fmaf(r3, m2k, ck);
        unsigned b4 = (unsigned)fmaf(r4, m2k, ck);
        unsigned b5 = (unsigned)fmaf(r5, m2k, ck);
        unsigned b6 = (unsigned)fmaf(r6, m2k, ck);
        unsigned b7 = (unsigned)fmaf(r7, m2k, ck);

        uint2 o;
        o.x = b0 | (b1 << 8) | (b2 << 16) | (b3 << 24);
        o.y = b4 | (b5 << 8) | (b6 << 16) | (b7 << 24);
        *(uint2*)(A8 + (size_t)(off + i) * 64 + s * 8) = o;
        if (s == 0) esrc[off + i] = src;
    }
}

// ---------------------------------------------------------------------------
// Light step, 16 edges in flight per wave: lane = el*4 + q; lane reads uint4
// of A8 (rows s=2q and 2q+1), holds 2 accumulators. Bias hoisted via hsum.
// ---------------------------------------------------------------------------
__global__ __launch_bounds__(256) void step_kernel(
    const float* __restrict__ Hin, const float* __restrict__ hsIn,
    float* __restrict__ Hout, float* __restrict__ hsOut,
    const int* __restrict__ esrc, const int* __restrict__ rowptr,
    const unsigned char* __restrict__ A8, const float* __restrict__ Bsum,
    const float* __restrict__ W1, const float* __restrict__ b1,
    float* __restrict__ logitsOut)
{
    int v = blockIdx.x * 4 + (threadIdx.x >> 6);
    if (v >= V) return;
    int lane = threadIdx.x & 63;
    int el = lane >> 2, q = lane & 3;

    int p0 = rowptr[v], p1 = rowptr[v + 1];

    float accE = 0.0f, accO = 0.0f, csum = 0.0f;
    for (int p = p0 + el; p < p1; p += 16) {
        int src = esrc[p];
        uint4 au = *(const uint4*)(A8 + (size_t)p * 64 + q * 16);
        float4 h0 = *(const float4*)(Hin + src * 8);
        float4 h1 = *(const float4*)(Hin + src * 8 + 4);
        csum += hsIn[src];

        accE += (float)( au.x        & 0xff) * h0.x
              + (float)((au.x >>  8) & 0xff) * h0.y
              + (float)((au.x >> 16) & 0xff) * h0.z
              + (float)( au.x >> 24        ) * h0.w
              + (float)( au.y        & 0xff) * h1.x
              + (float)((au.y >>  8) & 0xff) * h1.y
              + (float)((au.y >> 16) & 0xff) * h1.z
              + (float)( au.y >> 24        ) * h1.w;
        accO += (float)( au.z        & 0xff) * h0.x
              + (float)((au.z >>  8) & 0xff) * h0.y
              + (float)((au.z >> 16) & 0xff) * h0.z
              + (float)( au.z >> 24        ) * h0.w
              + (float)( au.w        & 0xff) * h1.x
              + (float)((au.w >>  8) & 0xff) * h1.y
              + (float)((au.w >> 16) & 0xff) * h1.z
              + (float)( au.w >> 24        ) * h1.w;
    }
    accE += __shfl_xor(accE, 4);  accE += __shfl_xor(accE, 8);
    accE += __shfl_xor(accE, 16); accE += __shfl_xor(accE, 32);
    accO += __shfl_xor(accO, 4);  accO += __shfl_xor(accO, 8);
    accO += __shfl_xor(accO, 16); accO += __shfl_xor(accO, 32);
    csum += __shfl_xor(csum, 4);  csum += __shfl_xor(csum, 8);
    csum += __shfl_xor(csum, 16); csum += __shfl_xor(csum, 32);

    float hE = (accE - 128.0f * csum) * AS + Bsum[v * 8 + q * 2];
    float hO = (accO - 128.0f * csum) * AS + Bsum[v * 8 + q * 2 + 1];

    float t2 = hE + hO;
    t2 += __shfl_xor(t2, 1); t2 += __shfl_xor(t2, 2);
    if (el == 0) {
        *(float2*)(Hout + v * 8 + q * 2) = make_float2(hE, hO);
        if (lane == 0) hsOut[v] = t2;
    }
    if (logitsOut != nullptr) {
        float t = hE * W1[q * 2] + hO * W1[q * 2 + 1];
        t += __shfl_xor(t, 1); t += __shfl_xor(t, 2);
        if (lane == 0) logitsOut[v] = t + b1[0];
    }
}

// ---------------------------------------------------------------------------
// Epilogue
// ---------------------------------------------------------------------------
__global__ __launch_bounds__(256) void reduce_max_kernel(
    const float* __restrict__ logits, float* __restrict__ partial)
{
    float m = -INFINITY;
    for (int v = blockIdx.x * 256 + threadIdx.x; v < V; v += 256 * 256)
        m = fmaxf(m, logits[v]);
    #pragma unroll
    for (int o = 32; o > 0; o >>= 1) m = fmaxf(m, __shfl_down(m, o));
    __shared__ float sm[4];
    if ((threadIdx.x & 63) == 0) sm[threadIdx.x >> 6] = m;
    __syncthreads();
    if (threadIdx.x == 0)
        partial[blockIdx.x] = fmaxf(fmaxf(sm[0], sm[1]), fmaxf(sm[2], sm[3]));
}

__global__ __launch_bounds__(256) void final_max_kernel(
    const float* __restrict__ partial, float* __restrict__ M)
{
    float m = partial[threadIdx.x];
    #pragma unroll
    for (int o = 32; o > 0; o >>= 1) m = fmaxf(m, __shfl_down(m, o));
    __shared__ float sm[4];
    if ((threadIdx.x & 63) == 0) sm[threadIdx.x >> 6] = m;
    __syncthreads();
    if (threadIdx.x == 0) *M = fmaxf(fmaxf(sm[0], sm[1]), fmaxf(sm[2], sm[3]));
}

// Stage 1: 64 blocks write per-block partials (9 floats each) — no atomics.
__global__ __launch_bounds__(256) void sum_kernel(
    const float* __restrict__ H, const float* __restrict__ logits,
    const float* __restrict__ Mp, float* __restrict__ partial)
{
    const float M = *Mp;
    float se = 0.0f;
    float sh[8] = {0, 0, 0, 0, 0, 0, 0, 0};
    for (int v = blockIdx.x * 256 + threadIdx.x; v < V; v += 64 * 256) {
        float w = __expf(logits[v] - M);
        se += w;
        const float4* H4 = (const float4*)(H + (size_t)v * 8);
        float4 h0 = H4[0], h1 = H4[1];
        sh[0] += w * h0.x; sh[1] += w * h0.y; sh[2] += w * h0.z; sh[3] += w * h0.w;
        sh[4] += w * h1.x; sh[5] += w * h1.y; sh[6] += w * h1.z; sh[7] += w * h1.w;
    }
    #pragma unroll
    for (int o = 32; o > 0; o >>= 1) {
        se += __shfl_xor(se, o);
        #pragma unroll
        for (int i = 0; i < 8; ++i) sh[i] += __shfl_xor(sh[i], o);
    }
    __shared__ float sm[4][9];
    int wv = threadIdx.x >> 6;
    if ((threadIdx.x & 63) == 0) {
        sm[wv][8] = se;
        #pragma unroll
        for (int i = 0; i < 8; ++i) sm[wv][i] = sh[i];
    }
    __syncthreads();
    if (threadIdx.x == 0) {
        #pragma unroll
        for (int i = 0; i < 9; ++i)
            partial[blockIdx.x * 12 + i] = sm[0][i] + sm[1][i] + sm[2][i] + sm[3][i];
    }
}

__global__ void final_kernel(const float* __restrict__ partial, float* __restrict__ out)
{
    int lane = threadIdx.x;               // 64 threads
    float vals[9];
    #pragma unroll
    for (int i = 0; i < 9; ++i) vals[i] = partial[lane * 12 + i];
    #pragma unroll
    for (int o = 1; o < 64; o <<= 1) {
        #pragma unroll
        for (int i = 0; i < 9; ++i) vals[i] += __shfl_xor(vals[i], o);
    }
    __shared__ float res[9];
    if (lane == 0) {
        #pragma unroll
        for (int i = 0; i < 9; ++i) res[i] = vals[i];
    }
    __syncthreads();
    if (lane < 8) out[lane] = tanhf(res[lane] / res[8]);
}

// ---------------------------------------------------------------------------
extern "C" void kernel_launch(void* const* d_in, const int* in_sizes, int n_in,
                              void* d_out, int out_size, void* d_ws, size_t ws_size,
                              hipStream_t stream)
{
    const float* feat  = (const float*)d_in[0];
    const int*   xnode = (const int*)d_in[1];
    const int*   xneis = (const int*)d_in[2];
    const int*   etype = (const int*)d_in[3];
    const float* dg    = (const float*)d_in[4];
    const float* Hinit = (const float*)d_in[5];
    const float* Wxi   = (const float*)d_in[6];
    const float* bxi   = (const float*)d_in[7];
    const float* Wrou  = (const float*)d_in[8];
    const float* brou  = (const float*)d_in[9];
    const float* W1    = (const float*)d_in[10];
    const float* b1    = (const float*)d_in[11];

    char* ws = (char*)d_ws;
    auto alloc = [&](size_t bytes) -> char* {
        char* p = ws; ws += (bytes + 255) & ~(size_t)255; return p;
    };
    // Budget: ~162 MB total (fits 256 MiB ws)
    unsigned char* A8 = (unsigned char*)alloc((size_t)E * 64); // 102.4 MB int8 A
    unsigned char* P8 = (unsigned char*)alloc((size_t)V * 64); // 6.4 MB int8 P
    ushort*   Qb      = (ushort*)alloc((size_t)V * 64 * 2);    // 12.8 MB bf16 Q
    unsigned* pmeta   = (unsigned*)alloc((size_t)E * 4);       // 6.4 MB partial CSR
    int*      esrc    = (int*)alloc((size_t)E * 4);            // 6.4 MB node-major src
    int*      countg  = (int*)alloc((size_t)2 * GV * 4);       // countg + cursorg
    int*      cursorg = countg + GV;
    int*      rpg     = (int*)alloc((size_t)GV * 4);           // 3.2 MB
    int*      cnt_tot = (int*)alloc((size_t)V * 4);
    int*      scannedT= (int*)alloc((size_t)V * 4);
    int*      rowptr  = (int*)alloc((size_t)(V + 1) * 4);
    int*      bsumT   = (int*)alloc(512 * 4);
    int*      topsT   = (int*)alloc(512 * 4);
    int*      bsumA   = (int*)alloc((size_t)NBG * 4);
    int*      sA      = (int*)alloc((size_t)NBG * 4);
    float*    B0      = (float*)alloc((size_t)V * 8 * 4);
    float*    B1      = (float*)alloc((size_t)V * 8 * 4);
    float*    Bsum    = (float*)alloc((size_t)V * 8 * 4);
    float*    hs0     = (float*)alloc((size_t)V * 4);
    float*    hsA     = (float*)alloc((size_t)V * 4);
    float*    hsB     = (float*)alloc((size_t)V * 4);
    float*    logits  = (float*)alloc((size_t)V * 4);
    float*    pmax    = (float*)alloc(256 * 4);
    float*    Mp      = (float*)alloc(16);
    float*    spart   = (float*)alloc(64 * 12 * 4);

    hipMemsetAsync(countg, 0, (size_t)2 * GV * 4, stream);
    histg_kernel<<<(E + 255) / 256, 256, 0, stream>>>(xneis, countg);
    // rowptr = scan(cnt_tot) with total at rowptr[V]; cnt_tot fused in
    scanV_kernel<<<NB, 256, 0, stream>>>(countg, cnt_tot, scannedT, bsumT);
    scan_tops_kernel<<<1, 512, 0, stream>>>(bsumT, topsT, rowptr);
    add_offsets_kernel<<<NB, 256, 0, stream>>>(scannedT, topsT, rowptr);
    // rpg = scan(countg) over the concatenated [g][v] array (2 levels)
    scan_block_kernel<<<NBG, 256, 0, stream>>>(countg, rpg, bsumA, GV);
    scan_mid_kernel<<<1, 256, 0, stream>>>(bsumA, sA, NBG);
    add_gen_kernel<<<NBG, 256, 0, stream>>>(rpg, sA, GV);

    scatterg_kernel<<<(E + 255) / 256, 256, 0, stream>>>(xnode, xneis, etype, dg,
                                                         rpg, cursorg, pmeta);
    pq_kernel<<<(V / 16 + 3) / 4, 256, 0, stream>>>(feat, Wxi, P8, Qb);
    bsum_kernel<<<NB, 256, 0, stream>>>(feat, cnt_tot, Wrou, brou, Hinit, Bsum, hs0);
    amat_kernel<<<(V + 3) / 4, 256, 0, stream>>>(pmeta, countg, rpg, rowptr,
                                                 P8, Qb, Wxi, bxi, A8, esrc);

    const float* Hcur = Hinit;
    const float* hsCur = hs0;
    float* bufs[2]   = {B0, B1};
    float* hsbufs[2] = {hsA, hsB};
    for (int t = 0; t < 4; ++t) {
        float* Hn  = bufs[t & 1];
        float* hsn = hsbufs[t & 1];
        float* lg  = (t == 3) ? logits : nullptr;
        step_kernel<<<(V + 3) / 4, 256, 0, stream>>>(Hcur, hsCur, Hn, hsn,
                                                     esrc, rowptr, A8, Bsum,
                                                     W1, b1, lg);
        Hcur = Hn; hsCur = hsn;
    }

    reduce_max_kernel<<<256, 256, 0, stream>>>(logits, pmax);
    final_max_kernel<<<1, 256, 0, stream>>>(pmax, Mp);
    sum_kernel<<<64, 256, 0, stream>>>(Hcur, logits, Mp, spart);
    final_kernel<<<1, 64, 0, stream>>>(spart, (float*)d_out);
}

// Round 16
// 527.789 us; speedup vs baseline: 1.0656x; 1.0157x over previous
//
#include <hip/hip_runtime.h>
#include <hip/hip_bf16.h>

constexpr int V   = 100000;
constexpr int E   = 1600000;
constexpr int NET = 10;
constexpr int KXW = 138;              // W_xi row length (2*64+10)
constexpr int NB  = (V + 255) / 256;  // 391 blocks over nodes
constexpr int GN  = 8;                // partial-CSR groups (≈ XCDs)
constexpr int GV  = GN * V;           // 800000
constexpr int NBG = (GV + 255) / 256; // 3125
constexpr float MUS   = 0.1125f;      // MU / S
constexpr float SP    = 0.025f;       // int8 P scale
constexpr float LOG2E = 1.44269504f;
constexpr float S2L   = 2.0f * SP * LOG2E;   // int8 P step in exp2 domain
constexpr float AS    = MUS / 127.0f;        // int8 A decode scale

typedef __attribute__((ext_vector_type(8))) short short8;
typedef __attribute__((ext_vector_type(4))) float float4v;

__device__ __forceinline__ float fast_tanh(float x) {
    return 1.0f - 2.0f * __builtin_amdgcn_rcpf(__expf(2.0f * x) + 1.0f);
}
__device__ __forceinline__ float bflo(unsigned u) { return __uint_as_float(u << 16); }
__device__ __forceinline__ float bfhi(unsigned u) { return __uint_as_float(u & 0xffff0000u); }
__device__ __forceinline__ short f2bf(float x) {
    union { __hip_bfloat16 b; short s; } u; u.b = __float2bfloat16(x); return u.s;
}

// Single-instruction byte->float converts (v_cvt_f32_ubyteN) with fallback.
__device__ __forceinline__ float ub0(unsigned u) {
#if __has_builtin(__builtin_amdgcn_cvt_f32_ubyte0)
    return __builtin_amdgcn_cvt_f32_ubyte0(u);
#else
    return (float)(u & 0xff);
#endif
}
__device__ __forceinline__ float ub1(unsigned u) {
#if __has_builtin(__builtin_amdgcn_cvt_f32_ubyte1)
    return __builtin_amdgcn_cvt_f32_ubyte1(u);
#else
    return (float)((u >> 8) & 0xff);
#endif
}
__device__ __forceinline__ float ub2(unsigned u) {
#if __has_builtin(__builtin_amdgcn_cvt_f32_ubyte2)
    return __builtin_amdgcn_cvt_f32_ubyte2(u);
#else
    return (float)((u >> 16) & 0xff);
#endif
}
__device__ __forceinline__ float ub3(unsigned u) {
#if __has_builtin(__builtin_amdgcn_cvt_f32_ubyte3)
    return __builtin_amdgcn_cvt_f32_ubyte3(u);
#else
    return (float)(u >> 24);
#endif
}
// f32 -> u8 insert-at-byte-pos (v_cvt_pk_u8_f32: cvt+clamp+insert in one op).
__device__ __forceinline__ unsigned pku8(float f, unsigned pos, unsigned old) {
#if __has_builtin(__builtin_amdgcn_cvt_pk_u8_f32)
    return __builtin_amdgcn_cvt_pk_u8_f32(f, pos, old);
#else
    return old | ((unsigned)f << (8 * pos));
#endif
}

// ---------------------------------------------------------------------------
// 8-way histogram: countg[g][v], g = blockIdx&7 (same grid as scatterg).
// ---------------------------------------------------------------------------
__global__ __launch_bounds__(256) void histg_kernel(
    const int* __restrict__ xneis, int* __restrict__ countg)
{
    int e = blockIdx.x * 256 + threadIdx.x;
    if (e >= E) return;
    int g = blockIdx.x & (GN - 1);
    int nr = xneis[e];
    if (nr < V) atomicAdd(&countg[g * V + nr], 1);
}

// Fused: cnt_tot[v] = sum_g countg[g][v]; blockwise-exclusive scan of cnt_tot.
__global__ __launch_bounds__(256) void scanV_kernel(
    const int* __restrict__ countg, int* __restrict__ cnt_tot,
    int* __restrict__ scanned, int* __restrict__ bsum)
{
    __shared__ int s[256];
    int tid = threadIdx.x;
    int i = blockIdx.x * 256 + tid;
    int c = 0;
    if (i < V) {
        #pragma unroll
        for (int g = 0; g < GN; ++g) c += countg[g * V + i];
        cnt_tot[i] = c;
    }
    s[tid] = c; __syncthreads();
    #pragma unroll
    for (int off = 1; off < 256; off <<= 1) {
        int t = (tid >= off) ? s[tid - off] : 0;
        __syncthreads();
        s[tid] += t;
        __syncthreads();
    }
    if (i < V) scanned[i] = s[tid] - c;
    if (tid == 255) bsum[blockIdx.x] = s[255];
}

// Generic block-exclusive scan (used for the GV level-0 scan).
__global__ __launch_bounds__(256) void scan_block_kernel(
    const int* __restrict__ in, int* __restrict__ out, int* __restrict__ bsum, int n)
{
    __shared__ int s[256];
    int tid = threadIdx.x;
    int i = blockIdx.x * 256 + tid;
    int v = (i < n) ? in[i] : 0;
    s[tid] = v; __syncthreads();
    #pragma unroll
    for (int off = 1; off < 256; off <<= 1) {
        int t = (tid >= off) ? s[tid - off] : 0;
        __syncthreads();
        s[tid] += t;
        __syncthreads();
    }
    if (i < n) out[i] = s[tid] - v;
    if (tid == 255) bsum[blockIdx.x] = s[255];
}

// Single-block full exclusive scan with running carry.
__global__ __launch_bounds__(256) void scan_mid_kernel(
    const int* __restrict__ in, int* __restrict__ out, int n)
{
    __shared__ int s[256];
    __shared__ int carry;
    int tid = threadIdx.x;
    if (tid == 0) carry = 0;
    __syncthreads();
    for (int base = 0; base < n; base += 256) {
        int i = base + tid;
        int x = (i < n) ? in[i] : 0;
        s[tid] = x; __syncthreads();
        #pragma unroll
        for (int off = 1; off < 256; off <<= 1) {
            int t = (tid >= off) ? s[tid - off] : 0;
            __syncthreads();
            s[tid] += t;
            __syncthreads();
        }
        int incl = s[tid];
        int c = carry;
        if (i < n) out[i] = c + incl - x;
        __syncthreads();
        if (tid == 255) carry = c + incl;
        __syncthreads();
    }
}

__global__ __launch_bounds__(256) void add_gen_kernel(
    int* __restrict__ arr, const int* __restrict__ tops, int n)
{
    int i = blockIdx.x * 256 + threadIdx.x;
    if (i < n) arr[i] += tops[i >> 8];
}

// rowptr path (V entries + total), NB <= 512
__global__ __launch_bounds__(512) void scan_tops_kernel(
    const int* __restrict__ blocksum, int* __restrict__ tops, int* __restrict__ rowptr)
{
    __shared__ int s[512];
    int tid = threadIdx.x;
    int v = (tid < NB) ? blocksum[tid] : 0;
    s[tid] = v; __syncthreads();
    #pragma unroll
    for (int off = 1; off < 512; off <<= 1) {
        int t = (tid >= off) ? s[tid - off] : 0;
        __syncthreads();
        s[tid] += t;
        __syncthreads();
    }
    if (tid < NB) tops[tid] = s[tid] - v;        // exclusive
    if (tid == 511) rowptr[V] = s[511];          // total kept edges
}

__global__ __launch_bounds__(256) void add_offsets_kernel(
    const int* __restrict__ scanned, const int* __restrict__ tops, int* __restrict__ rowptr)
{
    int i = blockIdx.x * 256 + threadIdx.x;
    if (i < V) rowptr[i] = scanned[i] + tops[blockIdx.x];
}

// Scatter into group-g partial CSR (g = blockIdx&7, same grid as histg).
// meta word: src (17 b) | et (4 b) | dg-1 (6 b)
__global__ __launch_bounds__(256) void scatterg_kernel(
    const int* __restrict__ xnode, const int* __restrict__ xneis,
    const int* __restrict__ etype, const float* __restrict__ dg,
    const int* __restrict__ rpg, int* __restrict__ cursorg,
    unsigned* __restrict__ pmeta)
{
    int e = blockIdx.x * 256 + threadIdx.x;
    if (e >= E) return;
    int g = blockIdx.x & (GN - 1);
    int nr = xneis[e];
    if (nr < V) {
        int idx = g * V + nr;
        int p = rpg[idx] + atomicAdd(&cursorg[idx], 1);
        unsigned src = (unsigned)(xnode[e] - 1);
        unsigned et  = (unsigned)(etype[e] - 1);
        unsigned dgi = (unsigned)dg[e] - 1;        // 0..63, exact
        pmeta[p] = src | (et << 17) | (dgi << 21);
    }
}

// ---------------------------------------------------------------------------
// Per-node bias sum + bf16 H_init + rounded row sums.
// hs0 is the rowsum of the bf16-ROUNDED Hinit so the step's -128*csum
// correction matches the gathered (rounded) values exactly.
// ---------------------------------------------------------------------------
__global__ __launch_bounds__(256) void bsum_kernel(
    const float* __restrict__ feat, const int* __restrict__ count,
    const float* __restrict__ Wrou, const float* __restrict__ brou,
    const float* __restrict__ Hinit, float* __restrict__ Bsum,
    ushort* __restrict__ Hb0, float* __restrict__ hs0)
{
    __shared__ float Wl[512];
    __shared__ float bl[8];
    int tid = threadIdx.x;
    for (int i = tid; i < 512; i += 256) Wl[i] = Wrou[i];
    if (tid < 8) bl[tid] = brou[tid];
    __syncthreads();

    int v = blockIdx.x * 256 + tid;
    if (v >= V) return;
    int c = count[v];
    float out[8] = {0, 0, 0, 0, 0, 0, 0, 0};
    if (c > 0) {                                  // c>0 implies v >= 1
        const float4* f4 = (const float4*)(feat + (size_t)(v - 1) * 64);
        float acc[8];
        #pragma unroll
        for (int s = 0; s < 8; ++s) acc[s] = bl[s];
        #pragma unroll 4
        for (int k = 0; k < 16; ++k) {
            float4 x = f4[k];
            #pragma unroll
            for (int s = 0; s < 8; ++s) {
                const float* w = &Wl[s * 64 + k * 4];
                acc[s] += x.x * w[0] + x.y * w[1] + x.z * w[2] + x.w * w[3];
            }
        }
        float fc = (float)c;
        #pragma unroll
        for (int s = 0; s < 8; ++s) out[s] = fc * fast_tanh(acc[s]);
    }
    float4* O = (float4*)(Bsum + (size_t)v * 8);
    O[0] = make_float4(out[0], out[1], out[2], out[3]);
    O[1] = make_float4(out[4], out[5], out[6], out[7]);

    // bf16 Hinit row + rounded rowsum
    const float* Hh = Hinit + (size_t)v * 8;
    uint4 pk;
    unsigned w0 = (unsigned)(ushort)f2bf(Hh[0]) | ((unsigned)(ushort)f2bf(Hh[1]) << 16);
    unsigned w1 = (unsigned)(ushort)f2bf(Hh[2]) | ((unsigned)(ushort)f2bf(Hh[3]) << 16);
    unsigned w2 = (unsigned)(ushort)f2bf(Hh[4]) | ((unsigned)(ushort)f2bf(Hh[5]) << 16);
    unsigned w3 = (unsigned)(ushort)f2bf(Hh[6]) | ((unsigned)(ushort)f2bf(Hh[7]) << 16);
    pk.x = w0; pk.y = w1; pk.z = w2; pk.w = w3;
    *(uint4*)(Hb0 + (size_t)v * 8) = pk;
    hs0[v] = bflo(w0) + bfhi(w0) + bflo(w1) + bfhi(w1)
           + bflo(w2) + bfhi(w2) + bflo(w3) + bfhi(w3);
}

// ---------------------------------------------------------------------------
// PQ GEMM (MFMA): P[v] -> int8 biased (6.4 MB), Q[v] -> bf16 (12.8 MB)
// ---------------------------------------------------------------------------
__global__ __launch_bounds__(256) void pq_kernel(
    const float* __restrict__ feat, const float* __restrict__ Wxi,
    unsigned char* __restrict__ P8, ushort* __restrict__ Qb)
{
    const int lane = threadIdx.x & 63, wave = threadIdx.x >> 6;
    const int quad = lane >> 4, l16 = lane & 15;

    short8 bP[4][2], bQ[4][2];
    #pragma unroll
    for (int nt = 0; nt < 4; ++nt) {
        #pragma unroll
        for (int ks = 0; ks < 2; ++ks) {
            const float* wp = Wxi + (size_t)(nt * 16 + l16) * KXW + ks * 32 + quad * 8;
            short8 p, q;
            #pragma unroll
            for (int j = 0; j < 8; ++j) { p[j] = f2bf(wp[j]); q[j] = f2bf(wp[64 + j]); }
            bP[nt][ks] = p; bQ[nt][ks] = q;
        }
    }

    int t = blockIdx.x * 4 + wave;
    if (t >= V / 16) return;
    int v0 = t * 16;

    const float* fp = feat + (size_t)(v0 + l16) * 64 + quad * 8;
    short8 a0, a1;
    #pragma unroll
    for (int j = 0; j < 8; ++j) { a0[j] = f2bf(fp[j]); a1[j] = f2bf(fp[32 + j]); }

    float4v accP[4], accQ[4];
    #pragma unroll
    for (int nt = 0; nt < 4; ++nt) {
        float4v z = {0.f, 0.f, 0.f, 0.f};
        z = __builtin_amdgcn_mfma_f32_16x16x32_bf16(a0, bP[nt][0], z, 0, 0, 0);
        z = __builtin_amdgcn_mfma_f32_16x16x32_bf16(a1, bP[nt][1], z, 0, 0, 0);
        accP[nt] = z;
        float4v w = {0.f, 0.f, 0.f, 0.f};
        w = __builtin_amdgcn_mfma_f32_16x16x32_bf16(a0, bQ[nt][0], w, 0, 0, 0);
        w = __builtin_amdgcn_mfma_f32_16x16x32_bf16(a1, bQ[nt][1], w, 0, 0, 0);
        accQ[nt] = w;
    }

    #pragma unroll
    for (int r = 0; r < 4; ++r) {
        int row = v0 + quad * 4 + r;
        #pragma unroll
        for (int nt = 0; nt < 4; ++nt) {
            int col = nt * 16 + l16;
            int q8 = (int)rintf(accP[nt][r] * (1.0f / SP)) + 128;
            q8 = min(max(q8, 0), 255);
            P8[row * 64 + col] = (unsigned char)q8;
            Qb[row * 64 + col] = (ushort)f2bf(accQ[nt][r]);
        }
    }
}

// ---------------------------------------------------------------------------
// A materialization + CSR finalization in ONE pass. Byte paths forced to
// single instructions: v_cvt_f32_ubyteN for P8 decode, v_cvt_pk_u8_f32 for
// the int8 encode+pack (r15 VALUBusy=81% at 4x the hand-counted op budget ->
// compiler wasn't fusing extract/convert/pack).
// ---------------------------------------------------------------------------
__global__ __launch_bounds__(256) void amat_kernel(
    const unsigned* __restrict__ pmeta, const int* __restrict__ countg,
    const int* __restrict__ rpg, const int* __restrict__ rowptr,
    const unsigned char* __restrict__ P8, const ushort* __restrict__ Qb,
    const float* __restrict__ Wxi, const float* __restrict__ bxi,
    unsigned char* __restrict__ A8, int* __restrict__ esrc)
{
    __shared__ float Wet2[NET * 64];     // 2*log2e*(Wxi[n][128+et]+bxi[n])
    __shared__ float scT[64];            // 127/dg
    int tid = threadIdx.x;
    for (int i = tid; i < NET * 64; i += 256) {
        int et = i >> 6, n = i & 63;
        Wet2[i] = 2.0f * LOG2E * (Wxi[n * KXW + 128 + et] + bxi[n]);
    }
    if (tid < 64) scT[tid] = 127.0f / (float)(tid + 1);
    __syncthreads();

    int v = blockIdx.x * 4 + (tid >> 6);
    if (v >= V) return;
    int lane = tid & 63;
    int el = lane >> 3, s = lane & 7;

    // 8-segment table (count, base) -> prefix
    int cg = 0, bg = 0;
    if (lane < 8) { cg = countg[lane * V + v]; bg = rpg[lane * V + v]; }
    int prefA[8], baseA[8];
    int pref = 0;
    #pragma unroll
    for (int g = 0; g < GN; ++g) {
        prefA[g] = pref;
        baseA[g] = __shfl(bg, g);
        pref += __shfl(cg, g);
    }
    const int deg = pref;
    const int off = rowptr[v];

    float q0, q1, q2, q3, q4, q5, q6, q7;
    {
        uint4 qu = *(const uint4*)(Qb + v * 64 + s * 8);
        const float B = 128.0f * SP, C = 2.0f * LOG2E;
        q0 = C * (bflo(qu.x) - B); q1 = C * (bfhi(qu.x) - B);
        q2 = C * (bflo(qu.y) - B); q3 = C * (bfhi(qu.y) - B);
        q4 = C * (bflo(qu.z) - B); q5 = C * (bfhi(qu.z) - B);
        q6 = C * (bflo(qu.w) - B); q7 = C * (bfhi(qu.w) - B);
    }

    for (int i = el; i < deg; i += 8) {
        int gg = 0;
        #pragma unroll
        for (int g = 1; g < GN; ++g) if (i >= prefA[g]) gg = g;
        int p = baseA[gg] + (i - prefA[gg]);
        unsigned m = pmeta[p];
        int src = (int)(m & 0x1FFFF);
        int et  = (int)((m >> 17) & 0xF);
        float k   = scT[m >> 21];
        float m2k = -2.0f * k;
        float ck  = k + 128.5f;

        uint2 pu = *(const uint2*)(P8 + src * 64 + s * 8);
        const float4* w4 = (const float4*)(&Wet2[et * 64 + s * 8]);
        float4 wa = w4[0], wb = w4[1];

        float r0 = __builtin_amdgcn_rcpf(__builtin_amdgcn_exp2f(fmaf(ub0(pu.x), S2L, q0 + wa.x)) + 1.0f);
        float r1 = __builtin_amdgcn_rcpf(__builtin_amdgcn_exp2f(fmaf(ub1(pu.x), S2L, q1 + wa.y)) + 1.0f);
        float r2 = __builtin_amdgcn_rcpf(__builtin_amdgcn_exp2f(fmaf(ub2(pu.x), S2L, q2 + wa.z)) + 1.0f);
        float r3 = __builtin_amdgcn_rcpf(__builtin_amdgcn_exp2f(fmaf(ub3(pu.x), S2L, q3 + wa.w)) + 1.0f);
        float r4 = __builtin_amdgcn_rcpf(__builtin_amdgcn_exp2f(fmaf(ub0(pu.y), S2L, q4 + wb.x)) + 1.0f);
        float r5 = __builtin_amdgcn_rcpf(__builtin_amdgcn_exp2f(fmaf(ub1(pu.y), S2L, q5 + wb.y)) + 1.0f);
        float r6 = __builtin_amdgcn_rcpf(__builtin_amdgcn_exp2f(fmaf(ub2(pu.y), S2L, q6 + wb.z)) + 1.0f);
        float r7 = __builtin_amdgcn_rcpf(__builtin_amdgcn_exp2f(fmaf(ub3(pu.y), S2L, q7 + wb.w)) + 1.0f);

        uint2 o;
        o.x = pku8(fmaf(r3, m2k, ck), 3,
              pku8(fmaf(r2, m2k, ck), 2,
              pku8(fmaf(r1, m2k, ck), 1,
              pku8(fmaf(r0, m2k, ck), 0, 0u))));
        o.y = pku8(fmaf(r7, m2k, ck), 3,
              pku8(fmaf(r6, m2k, ck), 2,
              pku8(fmaf(r5, m2k, ck), 1,
              pku8(fmaf(r4, m2k, ck), 0, 0u))));
        *(uint2*)(A8 + (size_t)(off + i) * 64 + s * 8) = o;
        if (s == 0) esrc[off + i] = src;
    }
}

// ---------------------------------------------------------------------------
// Light step, 16 edges/wave, bf16 H gathers (16 B row = one line; r15 used
// 32 B fp32 rows). v_cvt_f32_ubyteN for A8 decode. hs computed from the
// ROUNDED bf16 values so the -128*csum algebra is exact.
// ---------------------------------------------------------------------------
__global__ __launch_bounds__(256) void step_kernel(
    const ushort* __restrict__ HbIn, const float* __restrict__ hsIn,
    ushort* __restrict__ HbOut, float* __restrict__ hsOut,
    const int* __restrict__ esrc, const int* __restrict__ rowptr,
    const unsigned char* __restrict__ A8, const float* __restrict__ Bsum,
    const float* __restrict__ W1, const float* __restrict__ b1,
    float* __restrict__ logitsOut, float* __restrict__ HfpOut)
{
    int v = blockIdx.x * 4 + (threadIdx.x >> 6);
    if (v >= V) return;
    int lane = threadIdx.x & 63;
    int el = lane >> 2, q = lane & 3;

    int p0 = rowptr[v], p1 = rowptr[v + 1];

    float accE = 0.0f, accO = 0.0f, csum = 0.0f;
    for (int p = p0 + el; p < p1; p += 16) {
        int src = esrc[p];
        uint4 au = *(const uint4*)(A8 + (size_t)p * 64 + q * 16);
        uint4 hb = *(const uint4*)(HbIn + src * 8);   // 8 bf16 = 16 B
        csum += hsIn[src];
        float h0x = bflo(hb.x), h0y = bfhi(hb.x), h0z = bflo(hb.y), h0w = bfhi(hb.y);
        float h1x = bflo(hb.z), h1y = bfhi(hb.z), h1z = bflo(hb.w), h1w = bfhi(hb.w);

        accE += ub0(au.x) * h0x + ub1(au.x) * h0y + ub2(au.x) * h0z + ub3(au.x) * h0w
              + ub0(au.y) * h1x + ub1(au.y) * h1y + ub2(au.y) * h1z + ub3(au.y) * h1w;
        accO += ub0(au.z) * h0x + ub1(au.z) * h0y + ub2(au.z) * h0z + ub3(au.z) * h0w
              + ub0(au.w) * h1x + ub1(au.w) * h1y + ub2(au.w) * h1z + ub3(au.w) * h1w;
    }
    accE += __shfl_xor(accE, 4);  accE += __shfl_xor(accE, 8);
    accE += __shfl_xor(accE, 16); accE += __shfl_xor(accE, 32);
    accO += __shfl_xor(accO, 4);  accO += __shfl_xor(accO, 8);
    accO += __shfl_xor(accO, 16); accO += __shfl_xor(accO, 32);
    csum += __shfl_xor(csum, 4);  csum += __shfl_xor(csum, 8);
    csum += __shfl_xor(csum, 16); csum += __shfl_xor(csum, 32);

    float hE = (accE - 128.0f * csum) * AS + Bsum[v * 8 + q * 2];
    float hO = (accO - 128.0f * csum) * AS + Bsum[v * 8 + q * 2 + 1];

    // pack bf16 pair; rounded values drive next step's rowsum
    unsigned pk = (unsigned)(ushort)f2bf(hE) | ((unsigned)(ushort)f2bf(hO) << 16);
    float t2 = bflo(pk) + bfhi(pk);
    t2 += __shfl_xor(t2, 1); t2 += __shfl_xor(t2, 2);
    if (el == 0) {
        *(unsigned*)(HbOut + v * 8 + q * 2) = pk;
        if (lane == 0) hsOut[v] = t2;
        if (HfpOut != nullptr)
            *(float2*)(HfpOut + v * 8 + q * 2) = make_float2(hE, hO);
    }
    if (logitsOut != nullptr) {
        float t = hE * W1[q * 2] + hO * W1[q * 2 + 1];
        t += __shfl_xor(t, 1); t += __shfl_xor(t, 2);
        if (lane == 0) logitsOut[v] = t + b1[0];
    }
}

// ---------------------------------------------------------------------------
// Epilogue
// ---------------------------------------------------------------------------
__global__ __launch_bounds__(256) void reduce_max_kernel(
    const float* __restrict__ logits, float* __restrict__ partial)
{
    float m = -INFINITY;
    for (int v = blockIdx.x * 256 + threadIdx.x; v < V; v += 256 * 256)
        m = fmaxf(m, logits[v]);
    #pragma unroll
    for (int o = 32; o > 0; o >>= 1) m = fmaxf(m, __shfl_down(m, o));
    __shared__ float sm[4];
    if ((threadIdx.x & 63) == 0) sm[threadIdx.x >> 6] = m;
    __syncthreads();
    if (threadIdx.x == 0)
        partial[blockIdx.x] = fmaxf(fmaxf(sm[0], sm[1]), fmaxf(sm[2], sm[3]));
}

__global__ __launch_bounds__(256) void final_max_kernel(
    const float* __restrict__ partial, float* __restrict__ M)
{
    float m = partial[threadIdx.x];
    #pragma unroll
    for (int o = 32; o > 0; o >>= 1) m = fmaxf(m, __shfl_down(m, o));
    __shared__ float sm[4];
    if ((threadIdx.x & 63) == 0) sm[threadIdx.x >> 6] = m;
    __syncthreads();
    if (threadIdx.x == 0) *M = fmaxf(fmaxf(sm[0], sm[1]), fmaxf(sm[2], sm[3]));
}

// Stage 1: 64 blocks write per-block partials (9 floats each) — no atomics.
__global__ __launch_bounds__(256) void sum_kernel(
    const float* __restrict__ H, const float* __restrict__ logits,
    const float* __restrict__ Mp, float* __restrict__ partial)
{
    const float M = *Mp;
    float se = 0.0f;
    float sh[8] = {0, 0, 0, 0, 0, 0, 0, 0};
    for (int v = blockIdx.x * 256 + threadIdx.x; v < V; v += 64 * 256) {
        float w = __expf(logits[v] - M);
        se += w;
        const float4* H4 = (const float4*)(H + (size_t)v * 8);
        float4 h0 = H4[0], h1 = H4[1];
        sh[0] += w * h0.x; sh[1] += w * h0.y; sh[2] += w * h0.z; sh[3] += w * h0.w;
        sh[4] += w * h1.x; sh[5] += w * h1.y; sh[6] += w * h1.z; sh[7] += w * h1.w;
    }
    #pragma unroll
    for (int o = 32; o > 0; o >>= 1) {
        se += __shfl_xor(se, o);
        #pragma unroll
        for (int i = 0; i < 8; ++i) sh[i] += __shfl_xor(sh[i], o);
    }
    __shared__ float sm[4][9];
    int wv = threadIdx.x >> 6;
    if ((threadIdx.x & 63) == 0) {
        sm[wv][8] = se;
        #pragma unroll
        for (int i = 0; i < 8; ++i) sm[wv][i] = sh[i];
    }
    __syncthreads();
    if (threadIdx.x == 0) {
        #pragma unroll
        for (int i = 0; i < 9; ++i)
            partial[blockIdx.x * 12 + i] = sm[0][i] + sm[1][i] + sm[2][i] + sm[3][i];
    }
}

__global__ void final_kernel(const float* __restrict__ partial, float* __restrict__ out)
{
    int lane = threadIdx.x;               // 64 threads
    float vals[9];
    #pragma unroll
    for (int i = 0; i < 9; ++i) vals[i] = partial[lane * 12 + i];
    #pragma unroll
    for (int o = 1; o < 64; o <<= 1) {
        #pragma unroll
        for (int i = 0; i < 9; ++i) vals[i] += __shfl_xor(vals[i], o);
    }
    __shared__ float res[9];
    if (lane == 0) {
        #pragma unroll
        for (int i = 0; i < 9; ++i) res[i] = vals[i];
    }
    __syncthreads();
    if (lane < 8) out[lane] = tanhf(res[lane] / res[8]);
}

// ---------------------------------------------------------------------------
extern "C" void kernel_launch(void* const* d_in, const int* in_sizes, int n_in,
                              void* d_out, int out_size, void* d_ws, size_t ws_size,
                              hipStream_t stream)
{
    const float* feat  = (const float*)d_in[0];
    const int*   xnode = (const int*)d_in[1];
    const int*   xneis = (const int*)d_in[2];
    const int*   etype = (const int*)d_in[3];
    const float* dg    = (const float*)d_in[4];
    const float* Hinit = (const float*)d_in[5];
    const float* Wxi   = (const float*)d_in[6];
    const float* bxi   = (const float*)d_in[7];
    const float* Wrou  = (const float*)d_in[8];
    const float* brou  = (const float*)d_in[9];
    const float* W1    = (const float*)d_in[10];
    const float* b1    = (const float*)d_in[11];

    char* ws = (char*)d_ws;
    auto alloc = [&](size_t bytes) -> char* {
        char* p = ws; ws += (bytes + 255) & ~(size_t)255; return p;
    };
    // Budget: ~160 MB total (fits 256 MiB ws)
    unsigned char* A8 = (unsigned char*)alloc((size_t)E * 64); // 102.4 MB int8 A
    unsigned char* P8 = (unsigned char*)alloc((size_t)V * 64); // 6.4 MB int8 P
    ushort*   Qb      = (ushort*)alloc((size_t)V * 64 * 2);    // 12.8 MB bf16 Q
    unsigned* pmeta   = (unsigned*)alloc((size_t)E * 4);       // 6.4 MB partial CSR
    int*      esrc    = (int*)alloc((size_t)E * 4);            // 6.4 MB node-major src
    int*      countg  = (int*)alloc((size_t)2 * GV * 4);       // countg + cursorg
    int*      cursorg = countg + GV;
    int*      rpg     = (int*)alloc((size_t)GV * 4);           // 3.2 MB
    int*      cnt_tot = (int*)alloc((size_t)V * 4);
    int*      scannedT= (int*)alloc((size_t)V * 4);
    int*      rowptr  = (int*)alloc((size_t)(V + 1) * 4);
    int*      bsumT   = (int*)alloc(512 * 4);
    int*      topsT   = (int*)alloc(512 * 4);
    int*      bsumA   = (int*)alloc((size_t)NBG * 4);
    int*      sA      = (int*)alloc((size_t)NBG * 4);
    ushort*   Hb0     = (ushort*)alloc((size_t)V * 8 * 2);     // 1.6 MB bf16 H
    ushort*   HbA     = (ushort*)alloc((size_t)V * 8 * 2);
    ushort*   HbB     = (ushort*)alloc((size_t)V * 8 * 2);
    float*    Hfp     = (float*)alloc((size_t)V * 8 * 4);      // fp32 H (last step)
    float*    Bsum    = (float*)alloc((size_t)V * 8 * 4);
    float*    hs0     = (float*)alloc((size_t)V * 4);
    float*    hsA     = (float*)alloc((size_t)V * 4);
    float*    hsB     = (float*)alloc((size_t)V * 4);
    float*    logits  = (float*)alloc((size_t)V * 4);
    float*    pmax    = (float*)alloc(256 * 4);
    float*    Mp      = (float*)alloc(16);
    float*    spart   = (float*)alloc(64 * 12 * 4);

    hipMemsetAsync(countg, 0, (size_t)2 * GV * 4, stream);
    histg_kernel<<<(E + 255) / 256, 256, 0, stream>>>(xneis, countg);
    scanV_kernel<<<NB, 256, 0, stream>>>(countg, cnt_tot, scannedT, bsumT);
    scan_tops_kernel<<<1, 512, 0, stream>>>(bsumT, topsT, rowptr);
    add_offsets_kernel<<<NB, 256, 0, stream>>>(scannedT, topsT, rowptr);
    scan_block_kernel<<<NBG, 256, 0, stream>>>(countg, rpg, bsumA, GV);
    scan_mid_kernel<<<1, 256, 0, stream>>>(bsumA, sA, NBG);
    add_gen_kernel<<<NBG, 256, 0, stream>>>(rpg, sA, GV);

    scatterg_kernel<<<(E + 255) / 256, 256, 0, stream>>>(xnode, xneis, etype, dg,
                                                         rpg, cursorg, pmeta);
    pq_kernel<<<(V / 16 + 3) / 4, 256, 0, stream>>>(feat, Wxi, P8, Qb);
    bsum_kernel<<<NB, 256, 0, stream>>>(feat, cnt_tot, Wrou, brou, Hinit,
                                        Bsum, Hb0, hs0);
    amat_kernel<<<(V + 3) / 4, 256, 0, stream>>>(pmeta, countg, rpg, rowptr,
                                                 P8, Qb, Wxi, bxi, A8, esrc);

    const ushort* Hcur = Hb0;
    const float* hsCur = hs0;
    ushort* bufs[2]   = {HbA, HbB};
    float* hsbufs[2] = {hsA, hsB};
    for (int t = 0; t < 4; ++t) {
        ushort* Hn  = bufs[t & 1];
        float* hsn = hsbufs[t & 1];
        float* lg  = (t == 3) ? logits : nullptr;
        float* hf  = (t == 3) ? Hfp : nullptr;
        step_kernel<<<(V + 3) / 4, 256, 0, stream>>>(Hcur, hsCur, Hn, hsn,
                                                     esrc, rowptr, A8, Bsum,
                                                     W1, b1, lg, hf);
        Hcur = Hn; hsCur = hsn;
    }

    reduce_max_kernel<<<256, 256, 0, stream>>>(logits, pmax);
    final_max_kernel<<<1, 256, 0, stream>>>(pmax, Mp);
    sum_kernel<<<64, 256, 0, stream>>>(Hfp, logits, Mp, spart);
    final_kernel<<<1, 64, 0, stream>>>(spart, (float*)d_out);
}